// Round 8
// baseline (71.079 us; speedup 1.0000x reference)
//
#include <hip/hip_runtime.h>
#include <float.h>

#define BATCH 32
#define NP 512
#define NG 512
#define TSTEP 10
#define NI (NG * TSTEP)                   // 5120 candidates per batch
#define NCHUNK 16                         // chunks per batch
#define CH_CANDS (NI / NCHUNK)            // 320 cands per chunk
#define CH_PAIRS (CH_CANDS / 2)           // 160 float4 pairs per chunk
#define TILE_CANDS 16
#define TILE_PAIRS 8
#define TILES_CH (CH_PAIRS / TILE_PAIRS)  // 20 tiles per chunk
#define NB_SCAN (BATCH * NCHUNK)          // 512
#define NB_G2P 128                        // 4 blocks/batch, 128 gt pts each
#define NB_ALL (NB_SCAN + NB_G2P)         // 640
#define THR 128
#define RPT 4                             // preds per thread in scan
#define PRED_SLICE (NP / NCHUNK)          // 32 preds folded per scan block
#define NPRED (BATCH * NP)                // 16384

typedef float f2 __attribute__((ext_vector_type(2)));

__device__ __forceinline__ float wave_reduce(float v) {
#pragma unroll
    for (int o = 32; o > 0; o >>= 1) v += __shfl_down(v, o);
    return v;
}

// ---------------- K0: zero arrival counters (33 words) ----------------
__global__ __launch_bounds__(64) void k_init(unsigned int* __restrict__ counters) {
    if (threadIdx.x <= BATCH) counters[threadIdx.x] = 0u;
}

// ---------------- K1: everything ----------------
// blocks [0,512): (batch,chunk) scan -> plain-store packs; arrive counters[b];
//   spin till batch complete; fold+rescan a 32-pred slice -> psumB[bid].
// blocks [512,640): g2p -> gsum/msum.
// All blocks arrive at counters[BATCH]; the 640th computes the final scalar.
__global__ __launch_bounds__(THR) void k_main(
    const float* __restrict__ gt, const float* __restrict__ pred0,
    const float* __restrict__ pred1, const float* __restrict__ mask,
    unsigned long long* __restrict__ packs, float* __restrict__ psumB,
    float* __restrict__ gsum, float* __restrict__ msum,
    unsigned int* __restrict__ counters, float* __restrict__ out) {
    __shared__ float2 sTFU[TSTEP];
    __shared__ float4 sC4[CH_PAIRS];
    __shared__ float2 sP[NP];
    __shared__ float swl[2], swm[2], sred[6];
    __shared__ int sLast;
    const int bid = blockIdx.x, tid = threadIdx.x;

    if (bid < NB_SCAN) {
        const int b = bid >> 4, ch = bid & (NCHUNK - 1);
        const float* gtb = gt + b * NG * 2;
        if (tid < TSTEP) {
            float tf = (float)tid / 10.0f;           // same expr as rounds 1-7
            sTFU[tid] = make_float2(tf, 1.0f - tf);
        }
        __syncthreads();
        for (int k = tid; k < CH_PAIRS; k += THR) {  // stage — bitwise-identical to r7
            int k0 = ch * CH_CANDS + 2 * k, k1 = k0 + 1;
            int j0 = k0 / TSTEP, t0 = k0 - j0 * TSTEP;
            int j1 = k1 / TSTEP, t1 = k1 - j1 * TSTEP;
            int jm0 = (j0 + NG - 1) & (NG - 1), jm1 = (j1 + NG - 1) & (NG - 1);
            float2 w0 = sTFU[t0], w1 = sTFU[t1];
            float x0 = fmaf(gtb[2 * j0], w0.x, gtb[2 * jm0] * w0.y);
            float y0 = fmaf(gtb[2 * j0 + 1], w0.x, gtb[2 * jm0 + 1] * w0.y);
            float x1 = fmaf(gtb[2 * j1], w1.x, gtb[2 * jm1] * w1.y);
            float y1 = fmaf(gtb[2 * j1 + 1], w1.x, gtb[2 * jm1 + 1] * w1.y);
            sC4[k] = make_float4(x0, x1, y0, y1);
        }
        f2 PX[RPT], PY[RPT];
#pragma unroll
        for (int r = 0; r < RPT; ++r) {
            const float2 p = *(const float2*)(pred0 + (b * NP + r * THR + tid) * 2);
            PX[r] = (f2){p.x, p.x};
            PY[r] = (f2){p.y, p.y};
        }
        __syncthreads();

        // ---- hot loop: software-pipelined tile reads (prefetch t+1 while computing t) ----
        float4 cur[TILE_PAIRS], nxt[TILE_PAIRS];
#pragma unroll
        for (int j = 0; j < TILE_PAIRS; ++j) cur[j] = sC4[j];
        float best[RPT];
        int btile[RPT];
#pragma unroll
        for (int r = 0; r < RPT; ++r) { best[r] = FLT_MAX; btile[r] = 0; }
#pragma unroll 1
        for (int t = 0; t < TILES_CH; ++t) {
            const int tn = (t + 1 < TILES_CH) ? t + 1 : t;
#pragma unroll
            for (int j = 0; j < TILE_PAIRS; ++j) nxt[j] = sC4[tn * TILE_PAIRS + j];
            float acc[RPT];
#pragma unroll
            for (int r = 0; r < RPT; ++r) acc[r] = FLT_MAX;
#pragma unroll
            for (int q = 0; q < TILE_PAIRS; ++q) {
                const f2 cx = {cur[q].x, cur[q].y}, cy = {cur[q].z, cur[q].w};
#pragma unroll
                for (int r = 0; r < RPT; ++r) {
                    f2 dx = cx - PX[r], dy = cy - PY[r];
                    f2 d = __builtin_elementwise_fma(dy, dy, dx * dx);
                    acc[r] = fminf(fminf(d.x, d.y), acc[r]);   // v_min3
                }
            }
            const int tg = ch * TILES_CH + t;
#pragma unroll
            for (int r = 0; r < RPT; ++r)
                if (acc[r] < best[r]) { best[r] = acc[r]; btile[r] = tg; }  // strict <
#pragma unroll
            for (int j = 0; j < TILE_PAIRS; ++j) cur[j] = nxt[j];
        }
#pragma unroll
        for (int r = 0; r < RPT; ++r)
            packs[(size_t)ch * NPRED + b * NP + r * THR + tid] =
                ((unsigned long long)__float_as_uint(best[r]) << 32) | (unsigned)btile[r];

        // ---- arrive (release) + spin till all 16 chunks of this batch done ----
        if (tid == 0) {
            __hip_atomic_fetch_add(&counters[b], 1u, __ATOMIC_ACQ_REL,
                                   __HIP_MEMORY_SCOPE_AGENT);
            while (__hip_atomic_load(&counters[b], __ATOMIC_ACQUIRE,
                                     __HIP_MEMORY_SCOPE_AGENT) < NCHUNK)
                __builtin_amdgcn_s_sleep(2);
        }
        __syncthreads();   // visibility of all 16 chunks' packs chains to whole block

        // ---- fold+rescan our 32-pred slice (r7 k_comb body, bitwise-identical) ----
        float s = 0.0f;
        if (tid < PRED_SLICE) {
            const int pr = b * NP + ch * PRED_SLICE + tid;
            unsigned long long bp =
                __hip_atomic_load(&packs[pr], __ATOMIC_RELAXED, __HIP_MEMORY_SCOPE_AGENT);
#pragma unroll
            for (int c = 1; c < NCHUNK; ++c) {
                unsigned long long v = __hip_atomic_load(&packs[(size_t)c * NPRED + pr],
                                                         __ATOMIC_RELAXED,
                                                         __HIP_MEMORY_SCOPE_AGENT);
                if (v < bp) bp = v;
            }
            const float bestd = __uint_as_float((unsigned)(bp >> 32));
            const int wt = (int)(bp & 0xFFFFFFFFull);
            const float2 p = *(const float2*)(pred0 + pr * 2);
            const f2 pxx = {p.x, p.x}, pyy = {p.y, p.y};
            float nx = 0.f, ny = 0.f;
            bool found = false;
#pragma unroll
            for (int q = 0; q < TILE_PAIRS; ++q) {
                int k0 = wt * TILE_CANDS + 2 * q, k1 = k0 + 1;
                int j0 = k0 / TSTEP, t0 = k0 - j0 * TSTEP;
                int j1 = k1 / TSTEP, t1 = k1 - j1 * TSTEP;
                int jm0 = (j0 + NG - 1) & (NG - 1), jm1 = (j1 + NG - 1) & (NG - 1);
                float tf0 = (float)t0 / 10.0f, uf0 = 1.0f - tf0;
                float tf1 = (float)t1 / 10.0f, uf1 = 1.0f - tf1;
                float x0 = fmaf(gtb[2 * j0], tf0, gtb[2 * jm0] * uf0);
                float y0 = fmaf(gtb[2 * j0 + 1], tf0, gtb[2 * jm0 + 1] * uf0);
                float x1 = fmaf(gtb[2 * j1], tf1, gtb[2 * jm1] * uf1);
                float y1 = fmaf(gtb[2 * j1 + 1], tf1, gtb[2 * jm1 + 1] * uf1);
                f2 cx = {x0, x1}, cy = {y0, y1};
                f2 dx = cx - pxx, dy = cy - pyy;
                f2 d = __builtin_elementwise_fma(dy, dy, dx * dx);
                bool m0 = (d.x == bestd) && !found;
                nx = m0 ? x0 : nx; ny = m0 ? y0 : ny; found = found || m0;
                bool m1 = (d.y == bestd) && !found;
                nx = m1 ? x1 : nx; ny = m1 ? y1 : ny; found = found || m1;
            }
            s = fabsf(pred1[pr * 2] - nx) + fabsf(pred1[pr * 2 + 1] - ny);
        }
        s = wave_reduce(s);
        if ((tid & 63) == 0) swl[tid >> 6] = s;
        __syncthreads();
        if (tid == 0)
            __hip_atomic_store(&psumB[bid], swl[0] + swl[1], __ATOMIC_RELAXED,
                               __HIP_MEMORY_SCOPE_AGENT);
    } else {
        // ---------------- g2p: gt -> nearest pred (r7-proven body) ----------------
        const int gb = bid - NB_SCAN;        // 0..127
        const int b = gb >> 2, qd = gb & 3;
        for (int k = tid; k < NP; k += THR)
            sP[k] = make_float2(pred0[(b * NP + k) * 2], pred0[(b * NP + k) * 2 + 1]);
        __syncthreads();

        const int g = qd * THR + tid;
        const float gx = gt[(b * NG + g) * 2], gy = gt[(b * NG + g) * 2 + 1];
        float b0 = FLT_MAX, b1 = FLT_MAX;
        int i0 = 0, i1 = 0;
        const float4* s4 = (const float4*)sP;
#pragma unroll 4
        for (int i = 0; i < NP / 2; ++i) {
            float4 c = s4[i];
            float dx, dy, d;
            dx = gx - c.x; dy = gy - c.y; d = dx * dx + dy * dy;
            if (d < b0) { b0 = d; i0 = 2 * i; }
            dx = gx - c.z; dy = gy - c.w; d = dx * dx + dy * dy;
            if (d < b1) { b1 = d; i1 = 2 * i + 1; }
        }
        unsigned long long p0 = ((unsigned long long)__float_as_uint(b0) << 32) | (unsigned)i0;
        unsigned long long p1 = ((unsigned long long)__float_as_uint(b1) << 32) | (unsigned)i1;
        const int bi = (int)((p0 < p1 ? p0 : p1) & 0xFFFFFFFFull);
        const float m = mask[b * NG + g];
        float l = m * (fabsf(pred1[(b * NP + bi) * 2] - gx) +
                       fabsf(pred1[(b * NP + bi) * 2 + 1] - gy));
        float mm = 2.0f * m;
        l = wave_reduce(l);
        mm = wave_reduce(mm);
        if ((tid & 63) == 0) { swl[tid >> 6] = l; swm[tid >> 6] = mm; }
        __syncthreads();
        if (tid == 0) {
            __hip_atomic_store(&gsum[gb], swl[0] + swl[1], __ATOMIC_RELAXED,
                               __HIP_MEMORY_SCOPE_AGENT);
            __hip_atomic_store(&msum[gb], swm[0] + swm[1], __ATOMIC_RELAXED,
                               __HIP_MEMORY_SCOPE_AGENT);
        }
    }

    // ---------------- global arrival; 640th block computes the scalar ----------------
    if (tid == 0) {
        unsigned tk = __hip_atomic_fetch_add(&counters[BATCH], 1u, __ATOMIC_ACQ_REL,
                                             __HIP_MEMORY_SCOPE_AGENT);
        sLast = (tk == NB_ALL - 1);
    }
    __syncthreads();
    if (!sLast) return;

    float a = 0.0f;
#pragma unroll
    for (int i = 0; i < NB_SCAN / THR; ++i)
        a += __hip_atomic_load(&psumB[i * THR + tid], __ATOMIC_RELAXED,
                               __HIP_MEMORY_SCOPE_AGENT);
    float l = __hip_atomic_load(&gsum[tid], __ATOMIC_RELAXED, __HIP_MEMORY_SCOPE_AGENT);
    float m = __hip_atomic_load(&msum[tid], __ATOMIC_RELAXED, __HIP_MEMORY_SCOPE_AGENT);
    a = wave_reduce(a);
    l = wave_reduce(l);
    m = wave_reduce(m);
    if ((tid & 63) == 0) {
        int w = tid >> 6;
        sred[w * 3] = a; sred[w * 3 + 1] = l; sred[w * 3 + 2] = m;
    }
    __syncthreads();
    if (tid == 0) {
        float A = sred[0] + sred[3], L = sred[1] + sred[4], M = sred[2] + sred[5];
        out[0] = (L / (M + 1.0f) + A / (float)(NPRED * 2)) * 0.5f;
    }
}

extern "C" void kernel_launch(void* const* d_in, const int* in_sizes, int n_in,
                              void* d_out, int out_size, void* d_ws, size_t ws_size,
                              hipStream_t stream) {
    const float* pred0 = (const float*)d_in[0];   // ini_pred_poly [B,NP,2]
    const float* pred1 = (const float*)d_in[1];   // pred_polys_   [B,NP,2]
    const float* gt    = (const float*)d_in[2];   // gt_polys      [B,NG,2]
    const float* mask  = (const float*)d_in[3];   // keyPointsMask [B,NG]
    float* out = (float*)d_out;

    char* ws = (char*)d_ws;
    unsigned long long* packs = (unsigned long long*)ws;          // 16*16384*8 = 2 MB
    float* psumB = (float*)(ws + (size_t)NCHUNK * NPRED * 8);     // 512
    float* gsum = psumB + NB_SCAN;                                // 128
    float* msum = gsum + NB_G2P;                                  // 128
    unsigned int* counters = (unsigned int*)(msum + NB_G2P);      // 33

    hipLaunchKernelGGL(k_init, dim3(1), dim3(64), 0, stream, counters);
    hipLaunchKernelGGL(k_main, dim3(NB_ALL), dim3(THR), 0, stream,
                       gt, pred0, pred1, mask, packs, psumB, gsum, msum, counters, out);
}

// Round 9
// 41.729 us; speedup vs baseline: 1.7034x; 1.7034x over previous
//
#include <hip/hip_runtime.h>
#include <float.h>

#define BATCH 32
#define NP 512
#define NG 512
#define TSTEP 10
#define NI (NG * TSTEP)                   // 5120 candidates per batch
#define NCHUNK 64                         // chunks per batch (small chunks -> many waves)
#define CH_CANDS (NI / NCHUNK)            // 80 cands per chunk
#define CH_PAIRS (CH_CANDS / 2)           // 40 float4 pairs per chunk
#define TILE_CANDS 16
#define TILE_PAIRS 8
#define TILES_CH (CH_PAIRS / TILE_PAIRS)  // 5 tiles per chunk; 320 global tiles/batch
#define NB_SCAN ((BATCH / 2) * NCHUNK)    // 1024 blocks (each = 2 batch-teams)
#define NB_G2P 64                         // 2 blocks/batch, 256 gt pts each
#define THR 256
#define RPT 4                             // preds per thread (RPT*128 = NP per team)
#define NPRED (BATCH * NP)                // 16384
#define NB_COMB 256                       // k_comb blocks (64 thr, 1 pred/thread)

typedef float f2 __attribute__((ext_vector_type(2)));

__device__ __forceinline__ float wave_reduce(float v) {
#pragma unroll
    for (int o = 32; o > 0; o >>= 1) v += __shfl_down(v, o);
    return v;
}

// =================== K1: scan (high-occupancy, plain stores) + g2p ===================
// blocks [0,1024): (batch-pair, chunk). Two 128-thread teams, each team = one batch.
//   Team stages its 80-cand chunk in LDS, RPT=4 preds/thread, min-only per
//   16-cand tile, plain u64 store of (dist|tile). 4096 waves -> 4/SIMD.
// blocks [1024,1088): gt -> nearest pred (round-6-proven 256-thr body).
__global__ __launch_bounds__(THR) void k_scan(
    const float* __restrict__ gt, const float* __restrict__ pred0,
    const float* __restrict__ pred1, const float* __restrict__ mask,
    unsigned long long* __restrict__ packs,
    float* __restrict__ gsum, float* __restrict__ msum,
    unsigned int* __restrict__ counter) {
    __shared__ float2 sTFU[TSTEP];          // (tf, 1-tf) interp weights
    __shared__ float4 sC4[2][CH_PAIRS];     // per-team chunk candidates (x0,x1,y0,y1)
    __shared__ float2 sP[NP];               // g2p pred stage
    __shared__ float swl[4], swm[4];
    const int bid = blockIdx.x, tid = threadIdx.x;
    if (bid == NB_SCAN && tid == 0) *counter = 0u;   // re-arm K2's counter (r7-proven)

    if (bid < NB_SCAN) {
        const int bp = bid >> 6, ch = bid & (NCHUNK - 1);
        const int team = tid >> 7, ttid = tid & 127;
        const int b = bp * 2 + team;
        const float* gtb = gt + b * NG * 2;
        if (tid < TSTEP) {
            float tf = (float)tid / 10.0f;           // same expr as rounds 1-8
            sTFU[tid] = make_float2(tf, 1.0f - tf);
        }
        __syncthreads();
        if (ttid < CH_PAIRS) {   // stage 2 cands/thread — bitwise-identical exprs to r7
            int k0 = ch * CH_CANDS + 2 * ttid, k1 = k0 + 1;
            int j0 = k0 / TSTEP, t0 = k0 - j0 * TSTEP;
            int j1 = k1 / TSTEP, t1 = k1 - j1 * TSTEP;
            int jm0 = (j0 + NG - 1) & (NG - 1), jm1 = (j1 + NG - 1) & (NG - 1);
            float2 w0 = sTFU[t0], w1 = sTFU[t1];
            float x0 = fmaf(gtb[2 * j0], w0.x, gtb[2 * jm0] * w0.y);
            float y0 = fmaf(gtb[2 * j0 + 1], w0.x, gtb[2 * jm0 + 1] * w0.y);
            float x1 = fmaf(gtb[2 * j1], w1.x, gtb[2 * jm1] * w1.y);
            float y1 = fmaf(gtb[2 * j1 + 1], w1.x, gtb[2 * jm1 + 1] * w1.y);
            sC4[team][ttid] = make_float4(x0, x1, y0, y1);
        }
        f2 PX[RPT], PY[RPT];
#pragma unroll
        for (int r = 0; r < RPT; ++r) {
            const float2 p = *(const float2*)(pred0 + (b * NP + r * 128 + ttid) * 2);
            PX[r] = (f2){p.x, p.x};
            PY[r] = (f2){p.y, p.y};
        }
        __syncthreads();

        // ---- hot loop: simple r7-proven body (no reg pipelining), 4 waves/SIMD hide ----
        float best[RPT];
        int btile[RPT];
#pragma unroll
        for (int r = 0; r < RPT; ++r) { best[r] = FLT_MAX; btile[r] = 0; }
#pragma unroll 1
        for (int t = 0; t < TILES_CH; ++t) {
            float acc[RPT];
#pragma unroll
            for (int r = 0; r < RPT; ++r) acc[r] = FLT_MAX;
#pragma unroll
            for (int q = 0; q < TILE_PAIRS; ++q) {
                const float4 c = sC4[team][t * TILE_PAIRS + q];   // broadcast read
                const f2 cx = {c.x, c.y}, cy = {c.z, c.w};
#pragma unroll
                for (int r = 0; r < RPT; ++r) {
                    f2 dx = cx - PX[r], dy = cy - PY[r];
                    f2 d = __builtin_elementwise_fma(dy, dy, dx * dx);
                    acc[r] = fminf(fminf(d.x, d.y), acc[r]);   // v_min3
                }
            }
            const int tg = ch * TILES_CH + t;   // global 16-cand tile id, ascending
#pragma unroll
            for (int r = 0; r < RPT; ++r)
                if (acc[r] < best[r]) { best[r] = acc[r]; btile[r] = tg; }  // strict <
        }
        // dist>=0 -> bits monotone; tile in low bits -> u64 min = exact first-min tile.
#pragma unroll
        for (int r = 0; r < RPT; ++r)
            packs[(size_t)ch * NPRED + b * NP + r * 128 + ttid] =
                ((unsigned long long)__float_as_uint(best[r]) << 32) | (unsigned)btile[r];
    } else {
        // ---------------- g2p: gt -> nearest pred (round-6-proven body) ----------------
        const int gb = bid - NB_SCAN;        // 0..63
        const int b = gb >> 1, gh = gb & 1;
        for (int k = tid; k < NP; k += THR)
            sP[k] = make_float2(pred0[(b * NP + k) * 2], pred0[(b * NP + k) * 2 + 1]);
        __syncthreads();

        const int g = gh * 256 + tid;
        const float gx = gt[(b * NG + g) * 2], gy = gt[(b * NG + g) * 2 + 1];
        float b0 = FLT_MAX, b1 = FLT_MAX;
        int i0 = 0, i1 = 0;
        const float4* s4 = (const float4*)sP;
#pragma unroll 4
        for (int i = 0; i < NP / 2; ++i) {
            float4 c = s4[i];
            float dx, dy, d;
            dx = gx - c.x; dy = gy - c.y; d = dx * dx + dy * dy;
            if (d < b0) { b0 = d; i0 = 2 * i; }
            dx = gx - c.z; dy = gy - c.w; d = dx * dx + dy * dy;
            if (d < b1) { b1 = d; i1 = 2 * i + 1; }
        }
        unsigned long long p0 = ((unsigned long long)__float_as_uint(b0) << 32) | (unsigned)i0;
        unsigned long long p1 = ((unsigned long long)__float_as_uint(b1) << 32) | (unsigned)i1;
        const int bi = (int)((p0 < p1 ? p0 : p1) & 0xFFFFFFFFull);
        const float m = mask[b * NG + g];
        float l = m * (fabsf(pred1[(b * NP + bi) * 2] - gx) +
                       fabsf(pred1[(b * NP + bi) * 2 + 1] - gy));
        float mm = 2.0f * m;
        l = wave_reduce(l);
        mm = wave_reduce(mm);
        if ((tid & 63) == 0) { swl[tid >> 6] = l; swm[tid >> 6] = mm; }
        __syncthreads();
        if (tid == 0) {
            gsum[gb] = swl[0] + swl[1] + swl[2] + swl[3];
            msum[gb] = swm[0] + swm[1] + swm[2] + swm[3];
        }
    }
}

// =================== K2: fold + rescan + reduce + (last block) final ===================
// 256 blocks x 64 threads; thread = one pred point. Coalesced 64-pack fold,
// bitwise-identical rescan (r7-proven), last-arriver computes the scalar.
__global__ __launch_bounds__(64) void k_comb(
    const float* __restrict__ gt, const float* __restrict__ pred0,
    const float* __restrict__ pred1, const unsigned long long* __restrict__ packs,
    const float* __restrict__ gsum, const float* __restrict__ msum,
    float* __restrict__ psum, unsigned int* __restrict__ counter,
    float* __restrict__ out) {
    const int tid = threadIdx.x;
    const int pr = blockIdx.x * 64 + tid;
    const int b = pr >> 9;
    const float* gtb = gt + b * NG * 2;

    unsigned long long bp = packs[pr];
#pragma unroll 8
    for (int c = 1; c < NCHUNK; ++c) {
        unsigned long long v = packs[(size_t)c * NPRED + pr];
        if (v < bp) bp = v;
    }
    const float bestd = __uint_as_float((unsigned)(bp >> 32));
    const int wt = (int)(bp & 0xFFFFFFFFull);

    const float2 p = *(const float2*)(pred0 + pr * 2);
    const f2 pxx = {p.x, p.x}, pyy = {p.y, p.y};
    float nx = 0.f, ny = 0.f;
    bool found = false;
#pragma unroll
    for (int q = 0; q < TILE_PAIRS; ++q) {   // bitwise-identical recompute (r7-proven)
        int k0 = wt * TILE_CANDS + 2 * q, k1 = k0 + 1;
        int j0 = k0 / TSTEP, t0 = k0 - j0 * TSTEP;
        int j1 = k1 / TSTEP, t1 = k1 - j1 * TSTEP;
        int jm0 = (j0 + NG - 1) & (NG - 1), jm1 = (j1 + NG - 1) & (NG - 1);
        float tf0 = (float)t0 / 10.0f, uf0 = 1.0f - tf0;   // same bits as sTFU table
        float tf1 = (float)t1 / 10.0f, uf1 = 1.0f - tf1;
        float x0 = fmaf(gtb[2 * j0], tf0, gtb[2 * jm0] * uf0);
        float y0 = fmaf(gtb[2 * j0 + 1], tf0, gtb[2 * jm0 + 1] * uf0);
        float x1 = fmaf(gtb[2 * j1], tf1, gtb[2 * jm1] * uf1);
        float y1 = fmaf(gtb[2 * j1 + 1], tf1, gtb[2 * jm1 + 1] * uf1);
        f2 cx = {x0, x1}, cy = {y0, y1};
        f2 dx = cx - pxx, dy = cy - pyy;
        f2 d = __builtin_elementwise_fma(dy, dy, dx * dx);
        bool m0 = (d.x == bestd) && !found;
        nx = m0 ? x0 : nx; ny = m0 ? y0 : ny; found = found || m0;
        bool m1 = (d.y == bestd) && !found;
        nx = m1 ? x1 : nx; ny = m1 ? y1 : ny; found = found || m1;
    }
    float s = fabsf(pred1[pr * 2] - nx) + fabsf(pred1[pr * 2 + 1] - ny);
    s = wave_reduce(s);

    int lastFlag = 0;
    if (tid == 0) {
        __hip_atomic_store(&psum[blockIdx.x], s, __ATOMIC_RELAXED, __HIP_MEMORY_SCOPE_AGENT);
        unsigned tk = __hip_atomic_fetch_add(counter, 1u, __ATOMIC_ACQ_REL,
                                             __HIP_MEMORY_SCOPE_AGENT);
        lastFlag = (tk == NB_COMB - 1);
    }
    lastFlag = __shfl(lastFlag, 0);
    if (!lastFlag) return;

    // ---- final scalar (fixed-order reduce -> deterministic) ----
    float a = 0.0f;
#pragma unroll
    for (int i = 0; i < NB_COMB / 64; ++i)
        a += __hip_atomic_load(&psum[i * 64 + tid], __ATOMIC_RELAXED, __HIP_MEMORY_SCOPE_AGENT);
    float l = gsum[tid];      // 64 entries, written by K1 (kernel boundary)
    float m = msum[tid];
    a = wave_reduce(a);
    l = wave_reduce(l);
    m = wave_reduce(m);
    if (tid == 0)
        out[0] = (l / (m + 1.0f) + a / (float)(NPRED * 2)) * 0.5f;
}

extern "C" void kernel_launch(void* const* d_in, const int* in_sizes, int n_in,
                              void* d_out, int out_size, void* d_ws, size_t ws_size,
                              hipStream_t stream) {
    const float* pred0 = (const float*)d_in[0];   // ini_pred_poly [B,NP,2]
    const float* pred1 = (const float*)d_in[1];   // pred_polys_   [B,NP,2]
    const float* gt    = (const float*)d_in[2];   // gt_polys      [B,NG,2]
    const float* mask  = (const float*)d_in[3];   // keyPointsMask [B,NG]
    float* out = (float*)d_out;

    char* ws = (char*)d_ws;
    unsigned long long* packs = (unsigned long long*)ws;          // 64*16384*8 = 8 MB
    float* psum = (float*)(ws + (size_t)NCHUNK * NPRED * 8);      // 256
    float* gsum = psum + NB_COMB;                                 // 64
    float* msum = gsum + NB_G2P;                                  // 64
    unsigned int* counter = (unsigned int*)(msum + NB_G2P);       // 1

    hipLaunchKernelGGL(k_scan, dim3(NB_SCAN + NB_G2P), dim3(THR), 0, stream,
                       gt, pred0, pred1, mask, packs, gsum, msum, counter);
    hipLaunchKernelGGL(k_comb, dim3(NB_COMB), dim3(64), 0, stream,
                       gt, pred0, pred1, packs, gsum, msum, psum, counter, out);
}

// Round 10
// 33.484 us; speedup vs baseline: 2.1228x; 1.2462x over previous
//
#include <hip/hip_runtime.h>
#include <float.h>

#define BATCH 32
#define NP 512
#define NG 512
#define TSTEP 10
#define NI (NG * TSTEP)                   // 5120 candidates per batch
#define NCHUNK 16                         // chunks per batch
#define CH_CANDS (NI / NCHUNK)            // 320 cands per chunk
#define CH_PAIRS (CH_CANDS / 2)           // 160 float4 pairs per chunk
#define TILE_CANDS 16
#define TILE_PAIRS 8
#define TILES_CH (CH_PAIRS / TILE_PAIRS)  // 20 tiles per chunk
#define NB_SCAN (BATCH * NCHUNK)          // 512
#define NB_G2P 64                         // 2 blocks/batch, 256 gt pts each
#define THR 256
#define RPT 2                             // preds per thread (RPT*256 = NP)
#define NPRED (BATCH * NP)                // 16384
#define NB_COMB 128                       // k_comb blocks (128 thr, 1 pred/thread)

typedef float f2 __attribute__((ext_vector_type(2)));

__device__ __forceinline__ float wave_reduce(float v) {
#pragma unroll
    for (int o = 32; o > 0; o >>= 1) v += __shfl_down(v, o);
    return v;
}

// Compute one 8-pair tile from a register buffer; update per-tile acc.
__device__ __forceinline__ void tile_compute(const float4* buf, const f2* PX, const f2* PY,
                                             float* acc) {
#pragma unroll
    for (int q = 0; q < TILE_PAIRS; ++q) {
        const f2 cx = {buf[q].x, buf[q].y}, cy = {buf[q].z, buf[q].w};
#pragma unroll
        for (int r = 0; r < RPT; ++r) {
            f2 dx = cx - PX[r], dy = cy - PY[r];
            f2 d = __builtin_elementwise_fma(dy, dy, dx * dx);
            acc[r] = fminf(fminf(d.x, d.y), acc[r]);   // v_min3
        }
    }
}

// =================== K1: scan (pipelined LDS reads) + g2p ===================
// blocks [0,512): (batch,chunk) — stage 320-cand chunk in LDS; hot loop reads
//   tile t+1 into registers while computing tile t (latency hidden); min-only
//   per 16-cand tile; plain u64 (dist|tile) store. NO atomics.
// blocks [512,576): gt -> nearest pred (round-6-proven 256-thr body).
__global__ __launch_bounds__(THR, 2) void k_scan(
    const float* __restrict__ gt, const float* __restrict__ pred0,
    const float* __restrict__ pred1, const float* __restrict__ mask,
    unsigned long long* __restrict__ packs,
    float* __restrict__ gsum, float* __restrict__ msum,
    unsigned int* __restrict__ counter) {
    __shared__ float2 sTFU[TSTEP];      // (tf, 1-tf) interp weights
    __shared__ float4 sC4[CH_PAIRS];    // chunk candidates, pair layout (x0,x1,y0,y1)
    __shared__ float2 sP[NP];           // g2p pred stage
    __shared__ float swl[4], swm[4];
    const int bid = blockIdx.x, tid = threadIdx.x;
    if (bid == NB_SCAN && tid == 0) *counter = 0u;   // re-arm K2's counter (r7-proven)

    if (bid < NB_SCAN) {
        const int b = bid >> 4, ch = bid & (NCHUNK - 1);
        const float* gtb = gt + b * NG * 2;
        if (tid < TSTEP) {
            float tf = (float)tid / 10.0f;           // same expr as rounds 1-9
            sTFU[tid] = make_float2(tf, 1.0f - tf);
        }
        __syncthreads();
        if (tid < CH_PAIRS) {   // stage one pair/thread — bitwise-identical to r6
            int k0 = ch * CH_CANDS + 2 * tid, k1 = k0 + 1;
            int j0 = k0 / TSTEP, t0 = k0 - j0 * TSTEP;
            int j1 = k1 / TSTEP, t1 = k1 - j1 * TSTEP;
            int jm0 = (j0 + NG - 1) & (NG - 1), jm1 = (j1 + NG - 1) & (NG - 1);
            float2 w0 = sTFU[t0], w1 = sTFU[t1];
            float x0 = fmaf(gtb[2 * j0], w0.x, gtb[2 * jm0] * w0.y);
            float y0 = fmaf(gtb[2 * j0 + 1], w0.x, gtb[2 * jm0 + 1] * w0.y);
            float x1 = fmaf(gtb[2 * j1], w1.x, gtb[2 * jm1] * w1.y);
            float y1 = fmaf(gtb[2 * j1 + 1], w1.x, gtb[2 * jm1 + 1] * w1.y);
            sC4[tid] = make_float4(x0, x1, y0, y1);
        }
        f2 PX[RPT], PY[RPT];
#pragma unroll
        for (int r = 0; r < RPT; ++r) {
            const float2 p = *(const float2*)(pred0 + (b * NP + r * THR + tid) * 2);
            PX[r] = (f2){p.x, p.x};
            PY[r] = (f2){p.y, p.y};
        }
        __syncthreads();

        // ---- pipelined hot loop: A/B register buffers, static indices only ----
        float4 bufA[TILE_PAIRS], bufB[TILE_PAIRS];
#pragma unroll
        for (int j = 0; j < TILE_PAIRS; ++j) bufA[j] = sC4[j];          // tile 0
        float best[RPT];
        int btile[RPT];
#pragma unroll
        for (int r = 0; r < RPT; ++r) { best[r] = FLT_MAX; btile[r] = 0; }
#pragma unroll 1
        for (int tt = 0; tt < TILES_CH / 2; ++tt) {     // 2 tiles per iteration
            const int t0 = 2 * tt, t1 = 2 * tt + 1;
            // issue tile t1 loads, then compute tile t0 (loads in flight under VALU)
#pragma unroll
            for (int j = 0; j < TILE_PAIRS; ++j) bufB[j] = sC4[t1 * TILE_PAIRS + j];
            float acc0[RPT] = {FLT_MAX, FLT_MAX};
            tile_compute(bufA, PX, PY, acc0);
            const int tg0 = ch * TILES_CH + t0;
#pragma unroll
            for (int r = 0; r < RPT; ++r)
                if (acc0[r] < best[r]) { best[r] = acc0[r]; btile[r] = tg0; }  // strict <
            // issue tile t0+2 loads (clamped on last iter), compute tile t1
            const int tn = (tt + 1 < TILES_CH / 2) ? (t1 + 1) * TILE_PAIRS : 0;
#pragma unroll
            for (int j = 0; j < TILE_PAIRS; ++j) bufA[j] = sC4[tn + j];
            float acc1[RPT] = {FLT_MAX, FLT_MAX};
            tile_compute(bufB, PX, PY, acc1);
            const int tg1 = ch * TILES_CH + t1;
#pragma unroll
            for (int r = 0; r < RPT; ++r)
                if (acc1[r] < best[r]) { best[r] = acc1[r]; btile[r] = tg1; }
        }
        // dist>=0 -> bits monotone; tile in low bits -> u64 min = exact first-min tile.
#pragma unroll
        for (int r = 0; r < RPT; ++r)
            packs[(size_t)ch * NPRED + b * NP + r * THR + tid] =
                ((unsigned long long)__float_as_uint(best[r]) << 32) | (unsigned)btile[r];
    } else {
        // ---------------- g2p: gt -> nearest pred (round-6-proven body) ----------------
        const int gb = bid - NB_SCAN;        // 0..63
        const int b = gb >> 1, gh = gb & 1;
        for (int k = tid; k < NP; k += THR)
            sP[k] = make_float2(pred0[(b * NP + k) * 2], pred0[(b * NP + k) * 2 + 1]);
        __syncthreads();

        const int g = gh * 256 + tid;
        const float gx = gt[(b * NG + g) * 2], gy = gt[(b * NG + g) * 2 + 1];
        float b0 = FLT_MAX, b1 = FLT_MAX;
        int i0 = 0, i1 = 0;
        const float4* s4 = (const float4*)sP;
#pragma unroll 4
        for (int i = 0; i < NP / 2; ++i) {
            float4 c = s4[i];
            float dx, dy, d;
            dx = gx - c.x; dy = gy - c.y; d = dx * dx + dy * dy;
            if (d < b0) { b0 = d; i0 = 2 * i; }
            dx = gx - c.z; dy = gy - c.w; d = dx * dx + dy * dy;
            if (d < b1) { b1 = d; i1 = 2 * i + 1; }
        }
        unsigned long long p0 = ((unsigned long long)__float_as_uint(b0) << 32) | (unsigned)i0;
        unsigned long long p1 = ((unsigned long long)__float_as_uint(b1) << 32) | (unsigned)i1;
        const int bi = (int)((p0 < p1 ? p0 : p1) & 0xFFFFFFFFull);
        const float m = mask[b * NG + g];
        float l = m * (fabsf(pred1[(b * NP + bi) * 2] - gx) +
                       fabsf(pred1[(b * NP + bi) * 2 + 1] - gy));
        float mm = 2.0f * m;
        l = wave_reduce(l);
        mm = wave_reduce(mm);
        if ((tid & 63) == 0) { swl[tid >> 6] = l; swm[tid >> 6] = mm; }
        __syncthreads();
        if (tid == 0) {
            gsum[gb] = swl[0] + swl[1] + swl[2] + swl[3];
            msum[gb] = swm[0] + swm[1] + swm[2] + swm[3];
        }
    }
}

// =================== K2: fold + rescan + reduce + (last block) final ===================
// 128 blocks x 128 threads; thread = one pred point. Coalesced 16-pack fold,
// bitwise-identical rescan (r6/r7-proven), last-arriver computes the scalar.
__global__ __launch_bounds__(128) void k_comb(
    const float* __restrict__ gt, const float* __restrict__ pred0,
    const float* __restrict__ pred1, const unsigned long long* __restrict__ packs,
    const float* __restrict__ gsum, const float* __restrict__ msum,
    float* __restrict__ psum, unsigned int* __restrict__ counter,
    float* __restrict__ out) {
    __shared__ float sw[2], sred[6];
    __shared__ int sLast;
    const int tid = threadIdx.x;
    const int pr = blockIdx.x * 128 + tid;
    const int b = pr >> 9;
    const float* gtb = gt + b * NG * 2;

    unsigned long long bp = packs[pr];
#pragma unroll
    for (int c = 1; c < NCHUNK; ++c) {
        unsigned long long v = packs[(size_t)c * NPRED + pr];
        if (v < bp) bp = v;
    }
    const float bestd = __uint_as_float((unsigned)(bp >> 32));
    const int wt = (int)(bp & 0xFFFFFFFFull);

    const float2 p = *(const float2*)(pred0 + pr * 2);
    const f2 pxx = {p.x, p.x}, pyy = {p.y, p.y};
    float nx = 0.f, ny = 0.f;
    bool found = false;
#pragma unroll
    for (int q = 0; q < TILE_PAIRS; ++q) {   // bitwise-identical recompute (r6-proven)
        int k0 = wt * TILE_CANDS + 2 * q, k1 = k0 + 1;
        int j0 = k0 / TSTEP, t0 = k0 - j0 * TSTEP;
        int j1 = k1 / TSTEP, t1 = k1 - j1 * TSTEP;
        int jm0 = (j0 + NG - 1) & (NG - 1), jm1 = (j1 + NG - 1) & (NG - 1);
        float tf0 = (float)t0 / 10.0f, uf0 = 1.0f - tf0;   // same bits as sTFU table
        float tf1 = (float)t1 / 10.0f, uf1 = 1.0f - tf1;
        float x0 = fmaf(gtb[2 * j0], tf0, gtb[2 * jm0] * uf0);
        float y0 = fmaf(gtb[2 * j0 + 1], tf0, gtb[2 * jm0 + 1] * uf0);
        float x1 = fmaf(gtb[2 * j1], tf1, gtb[2 * jm1] * uf1);
        float y1 = fmaf(gtb[2 * j1 + 1], tf1, gtb[2 * jm1 + 1] * uf1);
        f2 cx = {x0, x1}, cy = {y0, y1};
        f2 dx = cx - pxx, dy = cy - pyy;
        f2 d = __builtin_elementwise_fma(dy, dy, dx * dx);
        bool m0 = (d.x == bestd) && !found;
        nx = m0 ? x0 : nx; ny = m0 ? y0 : ny; found = found || m0;
        bool m1 = (d.y == bestd) && !found;
        nx = m1 ? x1 : nx; ny = m1 ? y1 : ny; found = found || m1;
    }
    float s = fabsf(pred1[pr * 2] - nx) + fabsf(pred1[pr * 2 + 1] - ny);
    s = wave_reduce(s);
    if ((tid & 63) == 0) sw[tid >> 6] = s;
    __syncthreads();

    if (tid == 0) {
        __hip_atomic_store(&psum[blockIdx.x], sw[0] + sw[1], __ATOMIC_RELAXED,
                           __HIP_MEMORY_SCOPE_AGENT);
        unsigned tk = __hip_atomic_fetch_add(counter, 1u, __ATOMIC_ACQ_REL,
                                             __HIP_MEMORY_SCOPE_AGENT);
        sLast = (tk == NB_COMB - 1);
    }
    __syncthreads();
    if (!sLast) return;

    // ---- final scalar (fixed-order reduce -> deterministic) ----
    float a = __hip_atomic_load(&psum[tid], __ATOMIC_RELAXED, __HIP_MEMORY_SCOPE_AGENT);
    float l = tid < 64 ? gsum[tid] : 0.0f;   // written by K1 (kernel boundary)
    float m = tid < 64 ? msum[tid] : 0.0f;
    a = wave_reduce(a);
    l = wave_reduce(l);
    m = wave_reduce(m);
    if ((tid & 63) == 0) {
        int w = tid >> 6;
        sred[w * 3] = a; sred[w * 3 + 1] = l; sred[w * 3 + 2] = m;
    }
    __syncthreads();
    if (tid == 0) {
        float A = sred[0] + sred[3], L = sred[1] + sred[4], M = sred[2] + sred[5];
        out[0] = (L / (M + 1.0f) + A / (float)(NPRED * 2)) * 0.5f;
    }
}

extern "C" void kernel_launch(void* const* d_in, const int* in_sizes, int n_in,
                              void* d_out, int out_size, void* d_ws, size_t ws_size,
                              hipStream_t stream) {
    const float* pred0 = (const float*)d_in[0];   // ini_pred_poly [B,NP,2]
    const float* pred1 = (const float*)d_in[1];   // pred_polys_   [B,NP,2]
    const float* gt    = (const float*)d_in[2];   // gt_polys      [B,NG,2]
    const float* mask  = (const float*)d_in[3];   // keyPointsMask [B,NG]
    float* out = (float*)d_out;

    char* ws = (char*)d_ws;
    unsigned long long* packs = (unsigned long long*)ws;          // 16*16384*8 = 2 MB
    float* psum = (float*)(ws + (size_t)NCHUNK * NPRED * 8);      // 128
    float* gsum = psum + NB_COMB;                                 // 64
    float* msum = gsum + NB_G2P;                                  // 64
    unsigned int* counter = (unsigned int*)(msum + NB_G2P);       // 1

    hipLaunchKernelGGL(k_scan, dim3(NB_SCAN + NB_G2P), dim3(THR), 0, stream,
                       gt, pred0, pred1, mask, packs, gsum, msum, counter);
    hipLaunchKernelGGL(k_comb, dim3(NB_COMB), dim3(128), 0, stream,
                       gt, pred0, pred1, packs, gsum, msum, psum, counter, out);
}